// Round 19
// baseline (270.600 us; speedup 1.0000x reference)
//
#include <hip/hip_runtime.h>
#include <hip/hip_bf16.h>
#include <stdint.h>

// Problem constants
#define BB   2
#define SS   2048
#define HHH  2048
#define NHH  16
#define HDD  128
#define MTOT 4096   // BB*SS

typedef __bf16 bf16x8 __attribute__((ext_vector_type(8)));
typedef float  f32x4  __attribute__((ext_vector_type(4)));
typedef float  f32x16 __attribute__((ext_vector_type(16)));

#define MFMA16(a, b, c) __builtin_amdgcn_mfma_f32_16x16x32_bf16((a), (b), (c), 0, 0, 0)

__device__ __forceinline__ unsigned short f2bf(float f) {
    union { float f; unsigned u; } v; v.f = f;
    unsigned r = v.u + 0x7FFFu + ((v.u >> 16) & 1u);   // RNE
    return (unsigned short)(r >> 16);
}

__device__ __forceinline__ unsigned packbf(float a, float b) {
    union { __bf16 h[2]; unsigned u; } p;
    p.h[0] = (__bf16)a; p.h[1] = (__bf16)b;
    return p.u;
}

// v_permlane32_swap_b32: a' = [a.lo32, b.lo32], b' = [a.hi32, b.hi32]
__device__ __forceinline__ void pswap32(unsigned &a, unsigned &b) {
    asm("v_permlane32_swap_b32 %0, %1" : "+v"(a), "+v"(b));
}
// v_permlane16_swap_b32: within each 32-half: a' = [a.g_even, b.g_even], b' = [a.g_odd, b.g_odd]
__device__ __forceinline__ void pswap16(unsigned &a, unsigned &b) {
    asm("v_permlane16_swap_b32 %0, %1" : "+v"(a), "+v"(b));
}

// cross-half (lane ^ 32) pair via copy+swap
__device__ __forceinline__ float2 xswap32(float x) {
    unsigned a = __builtin_bit_cast(unsigned, x);
    unsigned b;
    asm("v_mov_b32 %0, %1" : "=v"(b) : "v"(a));
    asm("v_permlane32_swap_b32 %0, %1" : "+v"(a), "+v"(b));
    return make_float2(__builtin_bit_cast(float, a), __builtin_bit_cast(float, b));
}
// cross-16-group pair via copy+swap16: returns {even-group view, odd-group view}
__device__ __forceinline__ float2 xswap16(float x) {
    unsigned a = __builtin_bit_cast(unsigned, x);
    unsigned b;
    asm("v_mov_b32 %0, %1" : "=v"(b) : "v"(a));
    asm("v_permlane16_swap_b32 %0, %1" : "+v"(a), "+v"(b));
    return make_float2(__builtin_bit_cast(float, a), __builtin_bit_cast(float, b));
}

// async global->LDS, 16B per lane. LDS dest is wave-uniform base + lane*16.
__device__ __forceinline__ void gload16(const void* src, void* lds) {
    __builtin_amdgcn_global_load_lds(
        (__attribute__((address_space(1))) void*)src,
        (__attribute__((address_space(3))) void*)lds,
        16, 0, 0);
}

// ---------- merged prep (round-18 validated) ----------
__global__ void prep_all(const float* __restrict__ x, unsigned short* __restrict__ xb,
                         const float* __restrict__ mask, float* __restrict__ mkl,
                         const float* __restrict__ W0, const float* __restrict__ W1,
                         const float* __restrict__ W2, const float* __restrict__ W3,
                         unsigned short* __restrict__ Wt) {
    __shared__ float tile[32][33];
    int bid = blockIdx.x;
    if (bid < 16384) {
        int z = bid >> 12, rem = bid & 4095;
        int bx = rem & 63, by = rem >> 6;
        const float* in = z == 0 ? W0 : z == 1 ? W1 : z == 2 ? W2 : W3;
        unsigned short* o = Wt + (size_t)z * ((size_t)HHH * HHH);
        int c0 = bx * 32, r0 = by * 32;
        int tx = threadIdx.x & 31, ty = threadIdx.x >> 5;
        #pragma unroll
        for (int i = 0; i < 32; i += 8)
            tile[ty + i][tx] = in[(size_t)(r0 + ty + i) * HHH + c0 + tx];
        __syncthreads();
        #pragma unroll
        for (int i = 0; i < 32; i += 8)
            o[(size_t)(c0 + ty + i) * HHH + r0 + tx] = f2bf(tile[tx][ty + i]);
        return;
    }
    bid -= 16384;
    if (bid >= 2048) {
        int i = (bid - 2048) * 256 + threadIdx.x;
        mkl[i] = mask[i] * 1.4426950408889634f;
        return;
    }
    const int n = MTOT * HHH;
    const int stride = 2048 * 256 * 4;
    for (int i = (bid * 256 + threadIdx.x) * 4; i < n; i += stride) {
        float4 v = *(const float4*)(x + i);
        ushort4 o;
        o.x = f2bf(v.x); o.y = f2bf(v.y); o.z = f2bf(v.z); o.w = f2bf(v.w);
        *(ushort4*)(xb + i) = o;
    }
}

// ---------------- fused QK GEMM, 256x256 tile, 4-phase interleave (round-17/18) ---
__global__ __launch_bounds__(512, 2) void gemmQK(
    const unsigned short* __restrict__ A,
    const unsigned short* __restrict__ Bt,
    const float* __restrict__ bq,
    const float* __restrict__ bk,
    unsigned short* __restrict__ Qb,
    unsigned short* __restrict__ Kb)
{
    __shared__ __align__(16) unsigned char sm[131072];
    const int tid = threadIdx.x;
    const int wv = tid >> 6, ln = tid & 63;
    const int g = ln >> 4, r = ln & 15;
    const int wr = wv >> 2, wc = wv & 3;
    const int K = HHH;

    const int bid = blockIdx.x;
    const int xc = bid & 7, j = bid >> 3;
    const int m0 = ((xc >> 1) * 4 + (j & 3)) * 256;
    const int n0 = ((xc & 1) * 8 + (j >> 2)) * 256;

    unsigned srcA[4], srcB[4];
    int ldsA[4], ldsB[4];
    #pragma unroll
    for (int jj = 0; jj < 4; ++jj) {
        int o = jj * 8192 + tid * 16;
        int row = o >> 7;
        int lg = ((o >> 4) & 7) ^ (row & 7);
        srcA[jj] = (unsigned)(m0 + row) * K + lg * 8;
        srcB[jj] = (unsigned)(n0 + row) * K + lg * 8;
        ldsA[jj] = o;
        ldsB[jj] = 32768 + o;
    }

    f32x4 acc[8][4];
    #pragma unroll
    for (int i = 0; i < 8; ++i)
        #pragma unroll
        for (int jj = 0; jj < 4; ++jj)
            acc[i][jj] = (f32x4){0.f, 0.f, 0.f, 0.f};

    #pragma unroll
    for (int jj = 0; jj < 4; ++jj) { gload16(A + srcA[jj], sm + ldsA[jj]);
                                     gload16(Bt + srcB[jj], sm + ldsB[jj]); }
    #pragma unroll
    for (int jj = 0; jj < 4; ++jj) { gload16(A + srcA[jj] + 64, sm + 65536 + ldsA[jj]);
                                     gload16(Bt + srcB[jj] + 64, sm + 65536 + ldsB[jj]); }
    asm volatile("s_waitcnt vmcnt(8)" ::: "memory");
    __builtin_amdgcn_s_barrier();

    #define LDA(mi, ks) (*(const bf16x8*)(Ab + (wr * 128 + (mi) * 16 + r) * 128 + \
                         ((((ks) << 2) + g) ^ ((wr * 128 + (mi) * 16 + r) & 7)) * 16))
    #define LDB(ni, ks) (*(const bf16x8*)(Bb + (wc * 64 + (ni) * 16 + r) * 128 + \
                         ((((ks) << 2) + g) ^ ((wc * 64 + (ni) * 16 + r) & 7)) * 16))

    for (int t = 0; t < 32; ++t) {
        const int base = (t & 1) * 65536;
        const unsigned char* Ab = sm + base;
        const unsigned char* Bb = Ab + 32768;
        unsigned char* Pb = sm + base;
        const bool pre = (t + 2 < 32);
        const int ko = (t + 2) * 64;

        bf16x8 af[4][2], bfr[2][2];

        // ---- P0 (TL)
        #pragma unroll
        for (int mi = 0; mi < 4; ++mi) { af[mi][0] = LDA(mi, 0); af[mi][1] = LDA(mi, 1); }
        bfr[0][0] = LDB(0, 0); bfr[0][1] = LDB(0, 1);
        bfr[1][0] = LDB(1, 0); bfr[1][1] = LDB(1, 1);
        __builtin_amdgcn_s_barrier();
        asm volatile("s_waitcnt lgkmcnt(0)" ::: "memory");
        __builtin_amdgcn_s_setprio(1);
        #pragma unroll
        for (int mi = 0; mi < 4; ++mi)
            #pragma unroll
            for (int ni = 0; ni < 2; ++ni)
                #pragma unroll
                for (int ks = 0; ks < 2; ++ks)
                    acc[mi][ni] = MFMA16(af[mi][ks], bfr[ni][ks], acc[mi][ni]);
        __builtin_amdgcn_s_setprio(0);
        __builtin_amdgcn_s_barrier();

        // ---- P1 (TR)
        bfr[0][0] = LDB(2, 0); bfr[0][1] = LDB(2, 1);
        bfr[1][0] = LDB(3, 0); bfr[1][1] = LDB(3, 1);
        __builtin_amdgcn_s_barrier();
        asm volatile("s_waitcnt lgkmcnt(0)" ::: "memory");
        __builtin_amdgcn_s_setprio(1);
        #pragma unroll
        for (int mi = 0; mi < 4; ++mi)
            #pragma unroll
            for (int ni = 0; ni < 2; ++ni)
                #pragma unroll
                for (int ks = 0; ks < 2; ++ks)
                    acc[mi][ni + 2] = MFMA16(af[mi][ks], bfr[ni][ks], acc[mi][ni + 2]);
        __builtin_amdgcn_s_setprio(0);
        __builtin_amdgcn_s_barrier();

        // ---- P2 (BR): stage t+2 A_top
        #pragma unroll
        for (int mi = 0; mi < 4; ++mi) { af[mi][0] = LDA(mi + 4, 0); af[mi][1] = LDA(mi + 4, 1); }
        if (pre) { gload16(A + srcA[0] + ko, Pb + ldsA[0]);
                   gload16(A + srcA[1] + ko, Pb + ldsA[1]); }
        __builtin_amdgcn_s_barrier();
        asm volatile("s_waitcnt lgkmcnt(0)" ::: "memory");
        __builtin_amdgcn_s_setprio(1);
        #pragma unroll
        for (int mi = 0; mi < 4; ++mi)
            #pragma unroll
            for (int ni = 0; ni < 2; ++ni)
                #pragma unroll
                for (int ks = 0; ks < 2; ++ks)
                    acc[mi + 4][ni + 2] = MFMA16(af[mi][ks], bfr[ni][ks], acc[mi + 4][ni + 2]);
        __builtin_amdgcn_s_setprio(0);
        __builtin_amdgcn_s_barrier();

        // ---- P3 (BL): stage t+2 A_bot
        bfr[0][0] = LDB(0, 0); bfr[0][1] = LDB(0, 1);
        bfr[1][0] = LDB(1, 0); bfr[1][1] = LDB(1, 1);
        if (pre) { gload16(A + srcA[2] + ko, Pb + ldsA[2]);
                   gload16(A + srcA[3] + ko, Pb + ldsA[3]); }
        __builtin_amdgcn_s_barrier();
        asm volatile("s_waitcnt lgkmcnt(0)" ::: "memory");
        __builtin_amdgcn_s_setprio(1);
        #pragma unroll
        for (int mi = 0; mi < 4; ++mi)
            #pragma unroll
            for (int ni = 0; ni < 2; ++ni)
                #pragma unroll
                for (int ks = 0; ks < 2; ++ks)
                    acc[mi + 4][ni] = MFMA16(af[mi][ks], bfr[ni][ks], acc[mi + 4][ni]);
        __builtin_amdgcn_s_setprio(0);
        __builtin_amdgcn_s_barrier();

        if (pre) {
            #pragma unroll
            for (int jj = 0; jj < 4; ++jj)
                gload16(Bt + srcB[jj] + ko, Pb + ldsB[jj]);
            asm volatile("s_waitcnt vmcnt(8)" ::: "memory");
        } else {
            asm volatile("s_waitcnt vmcnt(0)" ::: "memory");
        }
        __builtin_amdgcn_s_barrier();
    }
    #undef LDA
    #undef LDB

    const int region = n0 >> 11;
    const float* bp = region ? bk : bq;
    unsigned short* outp = region ? Kb : Qb;
    #pragma unroll
    for (int mt = 0; mt < 8; ++mt) {
        #pragma unroll
        for (int nt = 0; nt < 4; ++nt) {
            int col = n0 + wc * 64 + nt * 16 + r;
            int lcol = col & 2047;
            float bvv = bp[lcol];
            f32x4 a = acc[mt][nt];
            int mrow = m0 + wr * 128 + mt * 16 + g * 4;
            #pragma unroll
            for (int q = 0; q < 4; ++q)
                outp[(size_t)(mrow + q) * 2048 + lcol] = f2bf(a[q] + bvv);
        }
    }
}

// ---------------- 2-phase GEMM (round-9 validated): V and O ----------------
template<int MODE>
__global__ __launch_bounds__(512, 2) void gemm8_bf16(
    const unsigned short* __restrict__ A,
    const unsigned short* __restrict__ Bt,
    const float* __restrict__ bias,
    void* __restrict__ Cout,
    int M, int N, int K)
{
    __shared__ __align__(16) unsigned char sm[147456];
    const int tid = threadIdx.x;
    const int wv = tid >> 6, ln = tid & 63;
    const int g = ln >> 4, r = ln & 15;
    const int wr = wv >> 2, wc = wv & 3;

    const int bid = blockIdx.x;
    const int xc = bid & 7, j = bid >> 3;
    const int m0 = ((xc & 3) * 8 + (j & 7)) * 128;
    const int n0 = ((xc >> 2) * 4 + (j >> 3)) * 256;

    unsigned srcA[2]; int ldsA[2];
    #pragma unroll
    for (int jj = 0; jj < 2; ++jj) {
        int o = jj * 8192 + tid * 16;
        int row = o >> 7;
        int lg = ((o >> 4) & 7) ^ (row & 7);
        srcA[jj] = (unsigned)(m0 + row) * K + lg * 8;
        ldsA[jj] = o;
    }
    unsigned srcB[4]; int ldsB[4];
    #pragma unroll
    for (int jj = 0; jj < 4; ++jj) {
        int o = jj * 8192 + tid * 16;
        int row = o >> 7;
        int lg = ((o >> 4) & 7) ^ (row & 7);
        srcB[jj] = (unsigned)(n0 + row) * K + lg * 8;
        ldsB[jj] = 16384 + o;
    }

    f32x4 acc[4][4];
    #pragma unroll
    for (int i = 0; i < 4; ++i)
        #pragma unroll
        for (int jj = 0; jj < 4; ++jj)
            acc[i][jj] = (f32x4){0.f, 0.f, 0.f, 0.f};

    const int NT = K >> 6;   // 32

    {
        unsigned char* b0 = sm;
        unsigned char* b1 = sm + 49152;
        #pragma unroll
        for (int jj = 0; jj < 2; ++jj) gload16(A + srcA[jj], b0 + ldsA[jj]);
        #pragma unroll
        for (int jj = 0; jj < 4; ++jj) gload16(Bt + srcB[jj], b0 + ldsB[jj]);
        #pragma unroll
        for (int jj = 0; jj < 2; ++jj) gload16(A + srcA[jj] + 64, b1 + ldsA[jj]);
        #pragma unroll
        for (int jj = 0; jj < 4; ++jj) gload16(Bt + srcB[jj] + 64, b1 + ldsB[jj]);
    }
    asm volatile("s_waitcnt vmcnt(6)" ::: "memory");
    __builtin_amdgcn_s_barrier();

    #define LDA(mi, ks) (*(const bf16x8*)(Ab + (wr * 64 + (mi) * 16 + r) * 128 + \
                         ((((ks) << 2) + g) ^ ((wr * 64 + (mi) * 16 + r) & 7)) * 16))
    #define LDB(ni, ks) (*(const bf16x8*)(Bb + (wc * 64 + (ni) * 16 + r) * 128 + \
                         ((((ks) << 2) + g) ^ ((wc * 64 + (ni) * 16 + r) & 7)) * 16))

    int csel = 0, psel = 2;
    for (int t = 0; t < NT; ++t) {
        const unsigned char* Ab = sm + csel * 49152;
        const unsigned char* Bb = Ab + 16384;
        unsigned char* Pb = sm + psel * 49152;
        const bool pre = (t + 2 < NT);
        const int ko = (t + 2) * 64;

        bf16x8 af[2][2], bfr[4][2];

        af[0][0] = LDA(0, 0); af[0][1] = LDA(0, 1);
        af[1][0] = LDA(1, 0); af[1][1] = LDA(1, 1);
        #pragma unroll
        for (int ni = 0; ni < 4; ++ni) { bfr[ni][0] = LDB(ni, 0); bfr[ni][1] = LDB(ni, 1); }
        if (pre) { gload16(Bt + srcB[0] + ko, Pb + ldsB[0]);
                   gload16(Bt + srcB[1] + ko, Pb + ldsB[1]);
                   gload16(Bt + srcB[2] + ko, Pb + ldsB[2]); }
        __builtin_amdgcn_s_barrier();
        asm volatile("s_waitcnt lgkmcnt(0)" ::: "memory");
        __builtin_amdgcn_s_setprio(1);
        #pragma unroll
        for (int mi = 0; mi < 2; ++mi)
            #pragma unroll
            for (int ni = 0; ni < 4; ++ni)
                #pragma unroll
                for (int ks = 0; ks < 2; ++ks)
                    acc[mi][ni] = MFMA16(af[mi][ks], bfr[ni][ks], acc[mi][ni]);
        __builtin_amdgcn_s_setprio(0);
        __builtin_amdgcn_s_barrier();

        af[0][0] = LDA(2, 0); af[0][1] = LDA(2, 1);
        af[1][0] = LDA(3, 0); af[1][1] = LDA(3, 1);
        if (pre) { gload16(Bt + srcB[3] + ko, Pb + ldsB[3]);
                   gload16(A + srcA[0] + ko, Pb + ldsA[0]);
                   gload16(A + srcA[1] + ko, Pb + ldsA[1]); }
        __builtin_amdgcn_s_barrier();
        asm volatile("s_waitcnt lgkmcnt(0)" ::: "memory");
        __builtin_amdgcn_s_setprio(1);
        #pragma unroll
        for (int mi = 0; mi < 2; ++mi)
            #pragma unroll
            for (int ni = 0; ni < 4; ++ni)
                #pragma unroll
                for (int ks = 0; ks < 2; ++ks)
                    acc[mi + 2][ni] = MFMA16(af[mi][ks], bfr[ni][ks], acc[mi + 2][ni]);
        __builtin_amdgcn_s_setprio(0);

        if (pre) asm volatile("s_waitcnt vmcnt(6)" ::: "memory");
        else     asm volatile("s_waitcnt vmcnt(0)" ::: "memory");
        __builtin_amdgcn_s_barrier();

        csel = (csel == 2) ? 0 : csel + 1;
        psel = (psel == 2) ? 0 : psel + 1;
    }
    #undef LDA
    #undef LDB

    #pragma unroll
    for (int mt = 0; mt < 4; ++mt) {
        #pragma unroll
        for (int nt = 0; nt < 4; ++nt) {
            int col = n0 + wc * 64 + nt * 16 + r;
            float bvv = bias[col];
            f32x4 a = acc[mt][nt];
            int mrow = m0 + wr * 64 + mt * 16 + g * 4;
            if (MODE == 0) {
                #pragma unroll
                for (int q = 0; q < 4; ++q)
                    ((unsigned short*)Cout)[(size_t)(mrow + q) * N + col] = f2bf(a[q] + bvv);
            } else if (MODE == 2) {
                #pragma unroll
                for (int q = 0; q < 4; ++q)
                    ((float*)Cout)[(size_t)(mrow + q) * N + col] = a[q] + bvv;
            } else {
                int b = mrow >> 11, s0x = mrow & 2047;
                ushort4 o;
                o.x = f2bf(a[0] + bvv); o.y = f2bf(a[1] + bvv);
                o.z = f2bf(a[2] + bvv); o.w = f2bf(a[3] + bvv);
                *(ushort4*)((unsigned short*)Cout + ((size_t)(b * 2048 + col)) * 2048 + s0x) = o;
            }
        }
    }
}

// ---------------- flash attention: 16x16 MFMA, 16 q-rows/wave, KVBLK=32 ----------------
// 1024 blocks (4 waves x 16 q = 64 q-rows each), LDS 40KB -> 3-4 blocks/CU (12-16
// waves/CU, vs 8 before). Swapped QK^T: S = mfma16(K,Q): lane holds S[key=4G+r][q=ln&15],
// G=ln>>4. Softmax in-register; cross-group reduce via permlane16/32 copy-swaps.
// P->PV B-frag: pack pairs + pswap32 + pswap16 (derived & element-checked).
// Staging/swizzles = round-9-validated KVBLK=32 set. Counted vmcnt(4), 2-buf.
__global__ __launch_bounds__(256, 3) void attn_fwd(
    const unsigned short* __restrict__ Q,
    const unsigned short* __restrict__ K,
    const unsigned short* __restrict__ V,
    const float* __restrict__ maskl2,   // mask * log2(e)
    unsigned short* __restrict__ O)
{
    __shared__ __align__(16) unsigned char sm[40960]; // 2 x 16KB KV bufs + 8KB mask @32768
    const int tid = threadIdx.x, wv = tid >> 6, ln = tid & 63;
    const int g = ln >> 4, q16 = ln & 15;

    // XCD-bijective swizzle (1024 = 8 XCD x 128): XCD owns 4 full heads
    const int bid = blockIdx.x;
    const int lb = (bid & 7) * 128 + (bid >> 3);
    const int qb = lb & 31;               // 32 q-blocks of 64 rows
    const int bh = lb >> 5;
    const int h = bh & 15, b = bh >> 4;

    const size_t rowQ0 = (size_t)(b * 2048 + qb * 64 + wv * 16);
    const float SCL2 = 0.08838834764831845f * 1.4426950408889634f; // scale*log2e

    // Q fragments FIRST (oldest vmem). B-operand: col=q16, k = ks*32 + g*8 + j
    bf16x8 qf[4];
    #pragma unroll
    for (int ks = 0; ks < 4; ++ks)
        qf[ks] = *(const bf16x8*)(Q + (rowQ0 + q16) * 2048 + h * 128 + ks * 32 + g * 8);

    // staging (round-9 KVBLK=32 set): K [32][128] 256B rows 16 granules ^(row&7);
    // Vt [128][32] 64B rows 4 granules ^((d>>1)&3)
    unsigned srcK[2], srcV[2];
    int ldsK[2], ldsV[2];
    #pragma unroll
    for (int i = 0; i < 2; ++i) {
        int ch = wv * 2 + i;
        int o = ch * 1024 + ln * 16;
        { int row = o >> 8; int gl = ((o >> 4) & 15) ^ (row & 7);
          srcK[i] = (unsigned)((b * 2048 + row) * 2048 + h * 128 + gl * 8);
          ldsK[i] = o; }
        { int d = o >> 6; int gl = ((o >> 4) & 3) ^ ((d >> 1) & 3);
          srcV[i] = (unsigned)((b * 2048 + h * 128 + d) * 2048 + gl * 8);
          ldsV[i] = 8192 + o; }
    }

    #define STAGE(t, base) { \
        _Pragma("unroll") \
        for (int i = 0; i < 2; ++i) { \
            gload16(K + srcK[i] + (unsigned)(t) * (32u * 2048u), sm + (base) + ldsK[i]); \
            gload16(V + srcV[i] + (unsigned)(t) * 32u, sm + (base) + ldsV[i]); \
        } }

    // mask row -> LDS (8KB, 2 issues/lane), then tiles 0,1
    #pragma unroll
    for (int it = 0; it < 2; ++it)
        gload16(maskl2 + b * 2048 + it * 1024 + wv * 256 + ln * 4,
                sm + 32768 + it * 4096 + wv * 1024 + ln * 16);
    STAGE(0, 0); STAGE(1, 16384);

    f32x4 acc[8];
    #pragma unroll
    for (int i = 0; i < 8; ++i)
        acc[i] = (f32x4){0.f, 0.f, 0.f, 0.f};
    float mr = -3.0e38f, lr = 0.f;   // per-lane: q = q16 (4 G-copies consistent)

    const float* ml = (const float*)(sm + 32768);

    // qf + mask + tile0 landed; tile1's 4 loads in flight
    asm volatile("s_waitcnt vmcnt(4)" ::: "memory");
    __builtin_amdgcn_s_barrier();

    for (int t = 0; t < 64; ++t) {
        const unsigned char* Kt = sm + (t & 1) * 16384;
        const unsigned char* Vt = Kt + 8192;

        // mask for this lane's keys: {4G+r} and {16+4G+r}
        f32x4 mk0 = *(const f32x4*)(ml + t * 32 + 4 * g);
        f32x4 mk1 = *(const f32x4*)(ml + t * 32 + 16 + 4 * g);

        // S = K Q^T : two independent 4-deep chains (keys 0-15 / 16-31)
        f32x4 S0 = (f32x4){0.f,0.f,0.f,0.f}, S1 = S0;
        __builtin_amdgcn_s_setprio(1);
        #pragma unroll
        for (int ks = 0; ks < 4; ++ks) {
            int row0 = q16, row1 = 16 + q16;
            int s0 = (ks * 4 + g) ^ (q16 & 7);
            bf16x8 kf0 = *(const bf16x8*)(Kt + row0 * 256 + s0 * 16);
            bf16x8 kf1 = *(const bf16x8*)(Kt + row1 * 256 + s0 * 16);
            S0 = MFMA16(kf0, qf[ks], S0);
            S1 = MFMA16(kf1, qf[ks], S1);
        }
        __builtin_amdgcn_s_setprio(0);

        // scale + mask (log2 domain)
        float sv[8];
        #pragma unroll
        for (int r2 = 0; r2 < 4; ++r2) {
            sv[r2]     = S0[r2] * SCL2 + mk0[r2];
            sv[4 + r2] = S1[r2] * SCL2 + mk1[r2];
        }

        // row max: in-lane 8, then cross-16-group, then cross-half
        float m01 = fmaxf(fmaxf(fmaxf(sv[0], sv[1]), fmaxf(sv[2], sv[3])),
                          fmaxf(fmaxf(sv[4], sv[5]), fmaxf(sv[6], sv[7])));
        float2 p16 = xswap16(m01);
        float m2 = fmaxf(p16.x, p16.y);
        float2 p32 = xswap32(m2);
        float mt = fmaxf(p32.x, p32.y);

        // defer-max
        float alpha = 1.f;
        int allskip = __all(mt <= mr + 8.f);
        if (!allskip) {
            float nm = fmaxf(mr, mt);
            alpha = __builtin_amdgcn_exp2f(mr - nm);
            mr = nm;
            #pragma unroll
            for (int dblk = 0; dblk < 8; ++dblk)
                #pragma unroll
                for (int r2 = 0; r2 < 4; ++r2)
                    acc[dblk][r2] *= alpha;
        }

        // P = exp2(S - m), row sum
        float s0 = 0.f;
        #pragma unroll
        for (int r2 = 0; r2 < 8; ++r2) {
            float p = __builtin_amdgcn_exp2f(sv[r2] - mr);
            sv[r2] = p;
            s0 += p;
        }
        float2 s16 = xswap16(s0);
        float s2 = s16.x + s16.y;
        float2 s32 = xswap32(s2);
        float rs = s32.x + s32.y;
        lr = lr * alpha + rs;

        // P -> PV B-frag: pack pairs, then pswap32 + pswap16
        // w0=[4G+0,1] w1=[4G+2,3] w2=[16+4G+0,1] w3=[16+4G+2,3]
        unsigned w0 = packbf(sv[0], sv[1]);
        unsigned w1 = packbf(sv[2], sv[3]);
        unsigned w2 = packbf(sv[4], sv[5]);
        unsigned w3 = packbf(sv[6], sv[7]);
        pswap32(w0, w2); pswap16(w0, w2);   // w0 -> word0, w2 -> word2
        pswap32(w1, w3); pswap16(w1, w3);   // w1 -> word1, w3 -> word3
        union { unsigned w[4]; bf16x8 v; } pu;
        pu.w[0] = w0; pu.w[1] = w1; pu.w[2] = w2; pu.w[3] = w3;

        // O += V^T P : A = V^T rows d (lane row = q16... d_local), k = keys g*8+j
        __builtin_amdgcn_s_setprio(1);
        #pragma unroll
        for (int dblk = 0; dblk < 8; ++dblk) {
            int d = dblk * 16 + q16;
            int s = g ^ ((d >> 1) & 3);
            bf16x8 vf = *(const bf16x8*)(Vt + d * 64 + s * 16);
            acc[dblk] = MFMA16(vf, pu.v, acc[dblk]);
        }
        __builtin_amdgcn_s_setprio(0);

        // tile end: refill freed buffer with t+2; counted wait (t+1 proven landed)
        __builtin_amdgcn_s_barrier();
        if (t + 2 < 64) {
            STAGE(t + 2, (t & 1) * 16384);
            asm volatile("s_waitcnt vmcnt(4)" ::: "memory");
        } else {
            asm volatile("s_waitcnt vmcnt(0)" ::: "memory");
        }
        __builtin_amdgcn_s_barrier();
    }
    #undef STAGE

    // epilogue: lane holds O[q=q16][d = dblk*16 + 4G + r2]; per-lane 1/l
    float linv = 1.f / lr;
    unsigned short* orow = O + (rowQ0 + q16) * 2048 + h * 128;
    #pragma unroll
    for (int dblk = 0; dblk < 8; ++dblk) {
        uint2 o;
        o.x = packbf(acc[dblk][0] * linv, acc[dblk][1] * linv);
        o.y = packbf(acc[dblk][2] * linv, acc[dblk][3] * linv);
        *(uint2*)(orow + dblk * 16 + 4 * g) = o;
    }
}

// ---------------- host launch ----------------
extern "C" void kernel_launch(void* const* d_in, const int* in_sizes, int n_in,
                              void* d_out, int out_size, void* d_ws, size_t ws_size,
                              hipStream_t stream)
{
    (void)in_sizes; (void)n_in; (void)out_size; (void)ws_size;
    const float* x    = (const float*)d_in[0];
    const float* mask = (const float*)d_in[1];
    const float* Wq   = (const float*)d_in[2];
    const float* bq   = (const float*)d_in[3];
    const float* Wk   = (const float*)d_in[4];
    const float* bk   = (const float*)d_in[5];
    const float* Wv   = (const float*)d_in[6];
    const float* bv   = (const float*)d_in[7];
    const float* Wo   = (const float*)d_in[8];
    const float* bo   = (const float*)d_in[9];
    float* out = (float*)d_out;

    char* ws = (char*)d_ws;
    unsigned short* xb  = (unsigned short*)(ws);
    unsigned short* Wqt = (unsigned short*)(ws + (16u << 20));   // Wqt|Wkt contiguous (QK B)
    unsigned short* Wvt = (unsigned short*)(ws + (32u << 20));
    unsigned short* Wot = (unsigned short*)(ws + (40u << 20));
    unsigned short* Qb  = (unsigned short*)(ws + (48u << 20));
    unsigned short* Kb  = (unsigned short*)(ws + (64u << 20));
    unsigned short* Vtb = (unsigned short*)(ws + (80u << 20));
    unsigned short* Ab  = (unsigned short*)(ws + (16u << 20));   // dead Wqt/Wkt after QK GEMM
    float*          mkl = out;                                   // scratch in d_out until gemmO

    prep_all<<<18436, 256, 0, stream>>>(x, xb, mask, mkl, Wq, Wk, Wv, Wo, Wqt);

    gemmQK<<<256, 512, 0, stream>>>(xb, Wqt, bq, bk, Qb, Kb);
    gemm8_bf16<1><<<256, 512, 0, stream>>>(xb, Wvt, bv, Vtb, MTOT, HHH, HHH);

    attn_fwd<<<1024, 256, 0, stream>>>(Qb, Kb, Vtb, mkl, Ab);

    gemm8_bf16<2><<<256, 512, 0, stream>>>(Ab, Wot, bo, out, MTOT, HHH, HHH);
}

// Round 20
// 256.693 us; speedup vs baseline: 1.0542x; 1.0542x over previous
//
#include <hip/hip_runtime.h>
#include <hip/hip_bf16.h>
#include <stdint.h>

// Problem constants
#define BB   2
#define SS   2048
#define HHH  2048
#define NHH  16
#define HDD  128
#define MTOT 4096   // BB*SS

typedef __bf16 bf16x8 __attribute__((ext_vector_type(8)));
typedef float  f32x4  __attribute__((ext_vector_type(4)));
typedef float  f32x16 __attribute__((ext_vector_type(16)));

#define MFMA16(a, b, c) __builtin_amdgcn_mfma_f32_16x16x32_bf16((a), (b), (c), 0, 0, 0)
#define MFMA32(a, b, c) __builtin_amdgcn_mfma_f32_32x32x16_bf16((a), (b), (c), 0, 0, 0)

__device__ __forceinline__ unsigned short f2bf(float f) {
    union { float f; unsigned u; } v; v.f = f;
    unsigned r = v.u + 0x7FFFu + ((v.u >> 16) & 1u);   // RNE
    return (unsigned short)(r >> 16);
}

__device__ __forceinline__ unsigned packbf(float a, float b) {
    union { __bf16 h[2]; unsigned u; } p;
    p.h[0] = (__bf16)a; p.h[1] = (__bf16)b;
    return p.u;
}

// v_permlane32_swap_b32: a' = [a.lo32, b.lo32], b' = [a.hi32, b.hi32]
__device__ __forceinline__ void pswap(unsigned &a, unsigned &b) {
    asm("v_permlane32_swap_b32 %0, %1" : "+v"(a), "+v"(b));
}

// cross-half (lane ^ 32) pair: returns {own-half view, other-half view}
__device__ __forceinline__ float2 xswap(float x) {
    unsigned a = __builtin_bit_cast(unsigned, x);
    unsigned b;
    asm("v_mov_b32 %0, %1" : "=v"(b) : "v"(a));   // force distinct register
    asm("v_permlane32_swap_b32 %0, %1" : "+v"(a), "+v"(b));
    return make_float2(__builtin_bit_cast(float, a), __builtin_bit_cast(float, b));
}

// async global->LDS, 16B per lane. LDS dest is wave-uniform base + lane*16.
__device__ __forceinline__ void gload16(const void* src, void* lds) {
    __builtin_amdgcn_global_load_lds(
        (__attribute__((address_space(1))) void*)src,
        (__attribute__((address_space(3))) void*)lds,
        16, 0, 0);
}

// ---------- merged prep (round-18 validated) ----------
__global__ void prep_all(const float* __restrict__ x, unsigned short* __restrict__ xb,
                         const float* __restrict__ mask, float* __restrict__ mkl,
                         const float* __restrict__ W0, const float* __restrict__ W1,
                         const float* __restrict__ W2, const float* __restrict__ W3,
                         unsigned short* __restrict__ Wt) {
    __shared__ float tile[32][33];
    int bid = blockIdx.x;
    if (bid < 16384) {
        int z = bid >> 12, rem = bid & 4095;
        int bx = rem & 63, by = rem >> 6;
        const float* in = z == 0 ? W0 : z == 1 ? W1 : z == 2 ? W2 : W3;
        unsigned short* o = Wt + (size_t)z * ((size_t)HHH * HHH);
        int c0 = bx * 32, r0 = by * 32;
        int tx = threadIdx.x & 31, ty = threadIdx.x >> 5;
        #pragma unroll
        for (int i = 0; i < 32; i += 8)
            tile[ty + i][tx] = in[(size_t)(r0 + ty + i) * HHH + c0 + tx];
        __syncthreads();
        #pragma unroll
        for (int i = 0; i < 32; i += 8)
            o[(size_t)(c0 + ty + i) * HHH + r0 + tx] = f2bf(tile[tx][ty + i]);
        return;
    }
    bid -= 16384;
    if (bid >= 2048) {
        int i = (bid - 2048) * 256 + threadIdx.x;
        mkl[i] = mask[i] * 1.4426950408889634f;
        return;
    }
    const int n = MTOT * HHH;
    const int stride = 2048 * 256 * 4;
    for (int i = (bid * 256 + threadIdx.x) * 4; i < n; i += stride) {
        float4 v = *(const float4*)(x + i);
        ushort4 o;
        o.x = f2bf(v.x); o.y = f2bf(v.y); o.z = f2bf(v.z); o.w = f2bf(v.w);
        *(ushort4*)(xb + i) = o;
    }
}

// ---------------- fused QK GEMM, 256x256 tile, 4-phase interleave (round-17/18) ---
__global__ __launch_bounds__(512, 2) void gemmQK(
    const unsigned short* __restrict__ A,
    const unsigned short* __restrict__ Bt,
    const float* __restrict__ bq,
    const float* __restrict__ bk,
    unsigned short* __restrict__ Qb,
    unsigned short* __restrict__ Kb)
{
    __shared__ __align__(16) unsigned char sm[131072];
    const int tid = threadIdx.x;
    const int wv = tid >> 6, ln = tid & 63;
    const int g = ln >> 4, r = ln & 15;
    const int wr = wv >> 2, wc = wv & 3;
    const int K = HHH;

    const int bid = blockIdx.x;
    const int xc = bid & 7, j = bid >> 3;
    const int m0 = ((xc >> 1) * 4 + (j & 3)) * 256;
    const int n0 = ((xc & 1) * 8 + (j >> 2)) * 256;

    unsigned srcA[4], srcB[4];
    int ldsA[4], ldsB[4];
    #pragma unroll
    for (int jj = 0; jj < 4; ++jj) {
        int o = jj * 8192 + tid * 16;
        int row = o >> 7;
        int lg = ((o >> 4) & 7) ^ (row & 7);
        srcA[jj] = (unsigned)(m0 + row) * K + lg * 8;
        srcB[jj] = (unsigned)(n0 + row) * K + lg * 8;
        ldsA[jj] = o;
        ldsB[jj] = 32768 + o;
    }

    f32x4 acc[8][4];
    #pragma unroll
    for (int i = 0; i < 8; ++i)
        #pragma unroll
        for (int jj = 0; jj < 4; ++jj)
            acc[i][jj] = (f32x4){0.f, 0.f, 0.f, 0.f};

    #pragma unroll
    for (int jj = 0; jj < 4; ++jj) { gload16(A + srcA[jj], sm + ldsA[jj]);
                                     gload16(Bt + srcB[jj], sm + ldsB[jj]); }
    #pragma unroll
    for (int jj = 0; jj < 4; ++jj) { gload16(A + srcA[jj] + 64, sm + 65536 + ldsA[jj]);
                                     gload16(Bt + srcB[jj] + 64, sm + 65536 + ldsB[jj]); }
    asm volatile("s_waitcnt vmcnt(8)" ::: "memory");
    __builtin_amdgcn_s_barrier();

    #define LDA(mi, ks) (*(const bf16x8*)(Ab + (wr * 128 + (mi) * 16 + r) * 128 + \
                         ((((ks) << 2) + g) ^ ((wr * 128 + (mi) * 16 + r) & 7)) * 16))
    #define LDB(ni, ks) (*(const bf16x8*)(Bb + (wc * 64 + (ni) * 16 + r) * 128 + \
                         ((((ks) << 2) + g) ^ ((wc * 64 + (ni) * 16 + r) & 7)) * 16))

    for (int t = 0; t < 32; ++t) {
        const int base = (t & 1) * 65536;
        const unsigned char* Ab = sm + base;
        const unsigned char* Bb = Ab + 32768;
        unsigned char* Pb = sm + base;
        const bool pre = (t + 2 < 32);
        const int ko = (t + 2) * 64;

        bf16x8 af[4][2], bfr[2][2];

        // ---- P0 (TL)
        #pragma unroll
        for (int mi = 0; mi < 4; ++mi) { af[mi][0] = LDA(mi, 0); af[mi][1] = LDA(mi, 1); }
        bfr[0][0] = LDB(0, 0); bfr[0][1] = LDB(0, 1);
        bfr[1][0] = LDB(1, 0); bfr[1][1] = LDB(1, 1);
        __builtin_amdgcn_s_barrier();
        asm volatile("s_waitcnt lgkmcnt(0)" ::: "memory");
        __builtin_amdgcn_s_setprio(1);
        #pragma unroll
        for (int mi = 0; mi < 4; ++mi)
            #pragma unroll
            for (int ni = 0; ni < 2; ++ni)
                #pragma unroll
                for (int ks = 0; ks < 2; ++ks)
                    acc[mi][ni] = MFMA16(af[mi][ks], bfr[ni][ks], acc[mi][ni]);
        __builtin_amdgcn_s_setprio(0);
        __builtin_amdgcn_s_barrier();

        // ---- P1 (TR)
        bfr[0][0] = LDB(2, 0); bfr[0][1] = LDB(2, 1);
        bfr[1][0] = LDB(3, 0); bfr[1][1] = LDB(3, 1);
        __builtin_amdgcn_s_barrier();
        asm volatile("s_waitcnt lgkmcnt(0)" ::: "memory");
        __builtin_amdgcn_s_setprio(1);
        #pragma unroll
        for (int mi = 0; mi < 4; ++mi)
            #pragma unroll
            for (int ni = 0; ni < 2; ++ni)
                #pragma unroll
                for (int ks = 0; ks < 2; ++ks)
                    acc[mi][ni + 2] = MFMA16(af[mi][ks], bfr[ni][ks], acc[mi][ni + 2]);
        __builtin_amdgcn_s_setprio(0);
        __builtin_amdgcn_s_barrier();

        // ---- P2 (BR): stage t+2 A_top
        #pragma unroll
        for (int mi = 0; mi < 4; ++mi) { af[mi][0] = LDA(mi + 4, 0); af[mi][1] = LDA(mi + 4, 1); }
        if (pre) { gload16(A + srcA[0] + ko, Pb + ldsA[0]);
                   gload16(A + srcA[1] + ko, Pb + ldsA[1]); }
        __builtin_amdgcn_s_barrier();
        asm volatile("s_waitcnt lgkmcnt(0)" ::: "memory");
        __builtin_amdgcn_s_setprio(1);
        #pragma unroll
        for (int mi = 0; mi < 4; ++mi)
            #pragma unroll
            for (int ni = 0; ni < 2; ++ni)
                #pragma unroll
                for (int ks = 0; ks < 2; ++ks)
                    acc[mi + 4][ni + 2] = MFMA16(af[mi][ks], bfr[ni][ks], acc[mi + 4][ni + 2]);
        __builtin_amdgcn_s_setprio(0);
        __builtin_amdgcn_s_barrier();

        // ---- P3 (BL): stage t+2 A_bot
        bfr[0][0] = LDB(0, 0); bfr[0][1] = LDB(0, 1);
        bfr[1][0] = LDB(1, 0); bfr[1][1] = LDB(1, 1);
        if (pre) { gload16(A + srcA[2] + ko, Pb + ldsA[2]);
                   gload16(A + srcA[3] + ko, Pb + ldsA[3]); }
        __builtin_amdgcn_s_barrier();
        asm volatile("s_waitcnt lgkmcnt(0)" ::: "memory");
        __builtin_amdgcn_s_setprio(1);
        #pragma unroll
        for (int mi = 0; mi < 4; ++mi)
            #pragma unroll
            for (int ni = 0; ni < 2; ++ni)
                #pragma unroll
                for (int ks = 0; ks < 2; ++ks)
                    acc[mi + 4][ni] = MFMA16(af[mi][ks], bfr[ni][ks], acc[mi + 4][ni]);
        __builtin_amdgcn_s_setprio(0);
        __builtin_amdgcn_s_barrier();

        if (pre) {
            #pragma unroll
            for (int jj = 0; jj < 4; ++jj)
                gload16(Bt + srcB[jj] + ko, Pb + ldsB[jj]);
            asm volatile("s_waitcnt vmcnt(8)" ::: "memory");
        } else {
            asm volatile("s_waitcnt vmcnt(0)" ::: "memory");
        }
        __builtin_amdgcn_s_barrier();
    }
    #undef LDA
    #undef LDB

    const int region = n0 >> 11;
    const float* bp = region ? bk : bq;
    unsigned short* outp = region ? Kb : Qb;
    #pragma unroll
    for (int mt = 0; mt < 8; ++mt) {
        #pragma unroll
        for (int nt = 0; nt < 4; ++nt) {
            int col = n0 + wc * 64 + nt * 16 + r;
            int lcol = col & 2047;
            float bvv = bp[lcol];
            f32x4 a = acc[mt][nt];
            int mrow = m0 + wr * 128 + mt * 16 + g * 4;
            #pragma unroll
            for (int q = 0; q < 4; ++q)
                outp[(size_t)(mrow + q) * 2048 + lcol] = f2bf(a[q] + bvv);
        }
    }
}

// ---------------- 2-phase GEMM (round-9 validated): V and O ----------------
template<int MODE>
__global__ __launch_bounds__(512, 2) void gemm8_bf16(
    const unsigned short* __restrict__ A,
    const unsigned short* __restrict__ Bt,
    const float* __restrict__ bias,
    void* __restrict__ Cout,
    int M, int N, int K)
{
    __shared__ __align__(16) unsigned char sm[147456];
    const int tid = threadIdx.x;
    const int wv = tid >> 6, ln = tid & 63;
    const int g = ln >> 4, r = ln & 15;
    const int wr = wv >> 2, wc = wv & 3;

    const int bid = blockIdx.x;
    const int xc = bid & 7, j = bid >> 3;
    const int m0 = ((xc & 3) * 8 + (j & 7)) * 128;
    const int n0 = ((xc >> 2) * 4 + (j >> 3)) * 256;

    unsigned srcA[2]; int ldsA[2];
    #pragma unroll
    for (int jj = 0; jj < 2; ++jj) {
        int o = jj * 8192 + tid * 16;
        int row = o >> 7;
        int lg = ((o >> 4) & 7) ^ (row & 7);
        srcA[jj] = (unsigned)(m0 + row) * K + lg * 8;
        ldsA[jj] = o;
    }
    unsigned srcB[4]; int ldsB[4];
    #pragma unroll
    for (int jj = 0; jj < 4; ++jj) {
        int o = jj * 8192 + tid * 16;
        int row = o >> 7;
        int lg = ((o >> 4) & 7) ^ (row & 7);
        srcB[jj] = (unsigned)(n0 + row) * K + lg * 8;
        ldsB[jj] = 16384 + o;
    }

    f32x4 acc[4][4];
    #pragma unroll
    for (int i = 0; i < 4; ++i)
        #pragma unroll
        for (int jj = 0; jj < 4; ++jj)
            acc[i][jj] = (f32x4){0.f, 0.f, 0.f, 0.f};

    const int NT = K >> 6;   // 32

    {
        unsigned char* b0 = sm;
        unsigned char* b1 = sm + 49152;
        #pragma unroll
        for (int jj = 0; jj < 2; ++jj) gload16(A + srcA[jj], b0 + ldsA[jj]);
        #pragma unroll
        for (int jj = 0; jj < 4; ++jj) gload16(Bt + srcB[jj], b0 + ldsB[jj]);
        #pragma unroll
        for (int jj = 0; jj < 2; ++jj) gload16(A + srcA[jj] + 64, b1 + ldsA[jj]);
        #pragma unroll
        for (int jj = 0; jj < 4; ++jj) gload16(Bt + srcB[jj] + 64, b1 + ldsB[jj]);
    }
    asm volatile("s_waitcnt vmcnt(6)" ::: "memory");
    __builtin_amdgcn_s_barrier();

    #define LDA(mi, ks) (*(const bf16x8*)(Ab + (wr * 64 + (mi) * 16 + r) * 128 + \
                         ((((ks) << 2) + g) ^ ((wr * 64 + (mi) * 16 + r) & 7)) * 16))
    #define LDB(ni, ks) (*(const bf16x8*)(Bb + (wc * 64 + (ni) * 16 + r) * 128 + \
                         ((((ks) << 2) + g) ^ ((wc * 64 + (ni) * 16 + r) & 7)) * 16))

    int csel = 0, psel = 2;
    for (int t = 0; t < NT; ++t) {
        const unsigned char* Ab = sm + csel * 49152;
        const unsigned char* Bb = Ab + 16384;
        unsigned char* Pb = sm + psel * 49152;
        const bool pre = (t + 2 < NT);
        const int ko = (t + 2) * 64;

        bf16x8 af[2][2], bfr[4][2];

        af[0][0] = LDA(0, 0); af[0][1] = LDA(0, 1);
        af[1][0] = LDA(1, 0); af[1][1] = LDA(1, 1);
        #pragma unroll
        for (int ni = 0; ni < 4; ++ni) { bfr[ni][0] = LDB(ni, 0); bfr[ni][1] = LDB(ni, 1); }
        if (pre) { gload16(Bt + srcB[0] + ko, Pb + ldsB[0]);
                   gload16(Bt + srcB[1] + ko, Pb + ldsB[1]);
                   gload16(Bt + srcB[2] + ko, Pb + ldsB[2]); }
        __builtin_amdgcn_s_barrier();
        asm volatile("s_waitcnt lgkmcnt(0)" ::: "memory");
        __builtin_amdgcn_s_setprio(1);
        #pragma unroll
        for (int mi = 0; mi < 2; ++mi)
            #pragma unroll
            for (int ni = 0; ni < 4; ++ni)
                #pragma unroll
                for (int ks = 0; ks < 2; ++ks)
                    acc[mi][ni] = MFMA16(af[mi][ks], bfr[ni][ks], acc[mi][ni]);
        __builtin_amdgcn_s_setprio(0);
        __builtin_amdgcn_s_barrier();

        af[0][0] = LDA(2, 0); af[0][1] = LDA(2, 1);
        af[1][0] = LDA(3, 0); af[1][1] = LDA(3, 1);
        if (pre) { gload16(Bt + srcB[3] + ko, Pb + ldsB[3]);
                   gload16(A + srcA[0] + ko, Pb + ldsA[0]);
                   gload16(A + srcA[1] + ko, Pb + ldsA[1]); }
        __builtin_amdgcn_s_barrier();
        asm volatile("s_waitcnt lgkmcnt(0)" ::: "memory");
        __builtin_amdgcn_s_setprio(1);
        #pragma unroll
        for (int mi = 0; mi < 2; ++mi)
            #pragma unroll
            for (int ni = 0; ni < 4; ++ni)
                #pragma unroll
                for (int ks = 0; ks < 2; ++ks)
                    acc[mi + 2][ni] = MFMA16(af[mi][ks], bfr[ni][ks], acc[mi + 2][ni]);
        __builtin_amdgcn_s_setprio(0);

        if (pre) asm volatile("s_waitcnt vmcnt(6)" ::: "memory");
        else     asm volatile("s_waitcnt vmcnt(0)" ::: "memory");
        __builtin_amdgcn_s_barrier();

        csel = (csel == 2) ? 0 : csel + 1;
        psel = (psel == 2) ? 0 : psel + 1;
    }
    #undef LDA
    #undef LDB

    #pragma unroll
    for (int mt = 0; mt < 4; ++mt) {
        #pragma unroll
        for (int nt = 0; nt < 4; ++nt) {
            int col = n0 + wc * 64 + nt * 16 + r;
            float bvv = bias[col];
            f32x4 a = acc[mt][nt];
            int mrow = m0 + wr * 64 + mt * 16 + g * 4;
            if (MODE == 0) {
                #pragma unroll
                for (int q = 0; q < 4; ++q)
                    ((unsigned short*)Cout)[(size_t)(mrow + q) * N + col] = f2bf(a[q] + bvv);
            } else if (MODE == 2) {
                #pragma unroll
                for (int q = 0; q < 4; ++q)
                    ((float*)Cout)[(size_t)(mrow + q) * N + col] = a[q] + bvv;
            } else {
                int b = mrow >> 11, s0x = mrow & 2047;
                ushort4 o;
                o.x = f2bf(a[0] + bvv); o.y = f2bf(a[1] + bvv);
                o.z = f2bf(a[2] + bvv); o.w = f2bf(a[3] + bvv);
                *(ushort4*)((unsigned short*)Cout + ((size_t)(b * 2048 + col)) * 2048 + s0x) = o;
            }
        }
    }
}

// ---------------- flash attention: KVBLK=64, 2-buf counted pipeline, mask in LDS ----------------
// Round-10/18 validated (~107 µs, VGPR 104).
__global__ __launch_bounds__(256, 2) void attn_fwd(
    const unsigned short* __restrict__ Q,
    const unsigned short* __restrict__ K,
    const unsigned short* __restrict__ V,
    const float* __restrict__ maskl2,   // mask * log2(e)
    unsigned short* __restrict__ O)
{
    __shared__ __align__(16) unsigned char sm[73728]; // 2 x 32KB KV bufs + 8KB mask @65536
    const int tid = threadIdx.x, wv = tid >> 6, ln = tid & 63;
    const int hi = ln >> 5, qr = ln & 31;

    const int bid = blockIdx.x;
    const int lb = (bid & 7) * 64 + (bid >> 3);
    const int qb = lb & 15;
    const int bh = lb >> 4;
    const int h = bh & 15, b = bh >> 4;

    const size_t rowQ0 = (size_t)(b * 2048 + qb * 128 + wv * 32);
    const float SCL2 = 0.08838834764831845f * 1.4426950408889634f; // scale*log2e

    unsigned srcK[4], srcV[4];
    int ldsK[4], ldsV[4];
    #pragma unroll
    for (int i = 0; i < 4; ++i) {
        int ch = wv * 4 + i;
        int o = ch * 1024 + ln * 16;
        { int row = o >> 8; int gl = ((o >> 4) & 15) ^ (row & 7);
          srcK[i] = (unsigned)((b * 2048 + row) * 2048 + h * 128 + gl * 8);
          ldsK[i] = o; }
        { int d = o >> 7; int gl = ((o >> 4) & 7) ^ (d & 7);
          srcV[i] = (unsigned)((b * 2048 + h * 128 + d) * 2048 + gl * 8);
          ldsV[i] = 16384 + o; }
    }

    #define STAGE(t, base) { \
        _Pragma("unroll") \
        for (int i = 0; i < 4; ++i) { \
            gload16(K + srcK[i] + (unsigned)(t) * (64u * 2048u), sm + (base) + ldsK[i]); \
            gload16(V + srcV[i] + (unsigned)(t) * 64u, sm + (base) + ldsV[i]); \
        } }

    #pragma unroll
    for (int i = 0; i < 2; ++i)
        gload16(maskl2 + b * 2048 + wv * 512 + i * 256 + ln * 4,
                sm + 65536 + wv * 2048 + i * 1024);
    STAGE(0, 0); STAGE(1, 32768);

    bf16x8 qf[8];
    #pragma unroll
    for (int ks = 0; ks < 8; ++ks)
        qf[ks] = *(const bf16x8*)(Q + (rowQ0 + qr) * 2048 + h * 128 + ks * 16 + hi * 8);

    f32x16 acc[4];
    #pragma unroll
    for (int i = 0; i < 4; ++i)
        #pragma unroll
        for (int jj = 0; jj < 16; ++jj)
            acc[i][jj] = 0.f;
    float mr = -3.0e38f, lr = 0.f;

    const float* ml = (const float*)(sm + 65536);

    asm volatile("s_waitcnt vmcnt(8)" ::: "memory");
    __builtin_amdgcn_s_barrier();

    for (int t = 0; t < 32; ++t) {
        const unsigned char* Kt = sm + (t & 1) * 32768;
        const unsigned char* Vt = Kt + 16384;

        f32x4 mk[2][4];
        #pragma unroll
        for (int kb2 = 0; kb2 < 2; ++kb2)
            #pragma unroll
            for (int rg = 0; rg < 4; ++rg)
                mk[kb2][rg] = *(const f32x4*)(ml + t * 64 + kb2 * 32 + rg * 8 + hi * 4);

        f32x16 sf0, sf1;
        #pragma unroll
        for (int jj = 0; jj < 16; ++jj) { sf0[jj] = 0.f; sf1[jj] = 0.f; }
        __builtin_amdgcn_s_setprio(1);
        #pragma unroll
        for (int ks = 0; ks < 8; ++ks) {
            int row0 = qr, row1 = 32 + qr;
            int s0 = ((2 * ks + hi) ^ (row0 & 7));
            int s1 = ((2 * ks + hi) ^ (row1 & 7));
            bf16x8 kf0 = *(const bf16x8*)(Kt + row0 * 256 + s0 * 16);
            bf16x8 kf1 = *(const bf16x8*)(Kt + row1 * 256 + s1 * 16);
            sf0 = MFMA32(kf0, qf[ks], sf0);
            sf1 = MFMA32(kf1, qf[ks], sf1);
        }
        __builtin_amdgcn_s_setprio(0);

        float sv[2][16];
        #pragma unroll
        for (int reg = 0; reg < 16; ++reg) {
            sv[0][reg] = sf0[reg] * SCL2 + mk[0][reg >> 2][reg & 3];
            sv[1][reg] = sf1[reg] * SCL2 + mk[1][reg >> 2][reg & 3];
        }

        float mx[8];
        #pragma unroll
        for (int jj = 0; jj < 8; ++jj)
            mx[jj] = fmaxf(fmaxf(sv[0][2*jj], sv[0][2*jj+1]),
                           fmaxf(sv[1][2*jj], sv[1][2*jj+1]));
        float m01 = fmaxf(fmaxf(fmaxf(mx[0], mx[1]), fmaxf(mx[2], mx[3])),
                          fmaxf(fmaxf(mx[4], mx[5]), fmaxf(mx[6], mx[7])));
        float2 mp = xswap(m01);
        float mt = fmaxf(mp.x, mp.y);

        float alpha = 1.f;
        int allskip = __all(mt <= mr + 8.f);
        if (!allskip) {
            float nm = fmaxf(mr, mt);
            alpha = __builtin_amdgcn_exp2f(mr - nm);
            mr = nm;
            #pragma unroll
            for (int dblk = 0; dblk < 4; ++dblk)
                #pragma unroll
                for (int reg = 0; reg < 16; ++reg)
                    acc[dblk][reg] *= alpha;
        }

        float s0 = 0.f, s1 = 0.f, s2 = 0.f, s3 = 0.f;
        #pragma unroll
        for (int kb2 = 0; kb2 < 2; ++kb2)
            #pragma unroll
            for (int reg = 0; reg < 16; reg += 4) {
                float p0 = __builtin_amdgcn_exp2f(sv[kb2][reg + 0] - mr);
                float p1 = __builtin_amdgcn_exp2f(sv[kb2][reg + 1] - mr);
                float p2 = __builtin_amdgcn_exp2f(sv[kb2][reg + 2] - mr);
                float p3 = __builtin_amdgcn_exp2f(sv[kb2][reg + 3] - mr);
                sv[kb2][reg + 0] = p0; sv[kb2][reg + 1] = p1;
                sv[kb2][reg + 2] = p2; sv[kb2][reg + 3] = p3;
                s0 += p0; s1 += p1; s2 += p2; s3 += p3;
            }
        float rsl = (s0 + s1) + (s2 + s3);
        float2 rp = xswap(rsl);
        float rs = rp.x + rp.y;
        lr = lr * alpha + rs;

        bf16x8 pfr[4];
        #pragma unroll
        for (int kb16 = 0; kb16 < 4; ++kb16) {
            const int kb2 = kb16 >> 1, i2 = kb16 & 1;
            float* pv = sv[kb2];
            unsigned W00 = packbf(pv[(2*i2+0)*4 + 0], pv[(2*i2+0)*4 + 1]);
            unsigned W01 = packbf(pv[(2*i2+0)*4 + 2], pv[(2*i2+0)*4 + 3]);
            unsigned W10 = packbf(pv[(2*i2+1)*4 + 0], pv[(2*i2+1)*4 + 1]);
            unsigned W11 = packbf(pv[(2*i2+1)*4 + 2], pv[(2*i2+1)*4 + 3]);
            pswap(W00, W10);
            pswap(W01, W11);
            union { unsigned w[4]; bf16x8 v; } u;
            u.w[0] = W00; u.w[1] = W01; u.w[2] = W10; u.w[3] = W11;
            pfr[kb16] = u.v;
        }

        __builtin_amdgcn_s_setprio(1);
        #pragma unroll
        for (int dblk = 0; dblk < 4; ++dblk) {
            int d = dblk * 32 + qr;
            f32x16 a = acc[dblk];
            #pragma unroll
            for (int kb16 = 0; kb16 < 4; ++kb16) {
                int s = ((2 * kb16 + hi) ^ (d & 7));
                bf16x8 vf = *(const bf16x8*)(Vt + d * 128 + s * 16);
                a = MFMA32(vf, pfr[kb16], a);
            }
            acc[dblk] = a;
        }
        __builtin_amdgcn_s_setprio(0);

        __builtin_amdgcn_s_barrier();
        if (t + 2 < 32) {
            STAGE(t + 2, (t & 1) * 32768);
            asm volatile("s_waitcnt vmcnt(8)" ::: "memory");
        } else {
            asm volatile("s_waitcnt vmcnt(0)" ::: "memory");
        }
        __builtin_amdgcn_s_barrier();
    }

    float linv = 1.f / lr;
    unsigned short* orow = O + (rowQ0 + qr) * 2048 + h * 128;
    #pragma unroll
    for (int dblk = 0; dblk < 4; ++dblk)
        #pragma unroll
        for (int rg = 0; rg < 4; ++rg) {
            float v0 = acc[dblk][rg * 4 + 0] * linv;
            float v1 = acc[dblk][rg * 4 + 1] * linv;
            float v2 = acc[dblk][rg * 4 + 2] * linv;
            float v3 = acc[dblk][rg * 4 + 3] * linv;
            uint2 o;
            o.x = packbf(v0, v1);
            o.y = packbf(v2, v3);
            *(uint2*)(orow + dblk * 32 + rg * 8 + hi * 4) = o;
        }
    #undef STAGE
}

// ---------------- host launch ----------------
extern "C" void kernel_launch(void* const* d_in, const int* in_sizes, int n_in,
                              void* d_out, int out_size, void* d_ws, size_t ws_size,
                              hipStream_t stream)
{
    (void)in_sizes; (void)n_in; (void)out_size; (void)ws_size;
    const float* x    = (const float*)d_in[0];
    const float* mask = (const float*)d_in[1];
    const float* Wq   = (const float*)d_in[2];
    const float* bq   = (const float*)d_in[3];
    const float* Wk   = (const float*)d_in[4];
    const float* bk   = (const float*)d_in[5];
    const float* Wv   = (const float*)d_in[6];
    const float* bv   = (const float*)d_in[7];
    const float* Wo   = (const float*)d_in[8];
    const float* bo   = (const float*)d_in[9];
    float* out = (float*)d_out;

    char* ws = (char*)d_ws;
    unsigned short* xb  = (unsigned short*)(ws);
    unsigned short* Wqt = (unsigned short*)(ws + (16u << 20));   // Wqt|Wkt contiguous (QK B)
    unsigned short* Wvt = (unsigned short*)(ws + (32u << 20));
    unsigned short* Wot = (unsigned short*)(ws + (40u << 20));
    unsigned short* Qb  = (unsigned short*)(ws + (48u << 20));
    unsigned short* Kb  = (unsigned short*)(ws + (64u << 20));
    unsigned short* Vtb = (unsigned short*)(ws + (80u << 20));
    unsigned short* Ab  = (unsigned short*)(ws + (16u << 20));   // dead Wqt/Wkt after QK GEMM
    float*          mkl = out;                                   // scratch in d_out until gemmO

    prep_all<<<18436, 256, 0, stream>>>(x, xb, mask, mkl, Wq, Wk, Wv, Wo, Wqt);

    gemmQK<<<256, 512, 0, stream>>>(xb, Wqt, bq, bk, Qb, Kb);
    gemm8_bf16<1><<<256, 512, 0, stream>>>(xb, Wvt, bv, Vtb, MTOT, HHH, HHH);

    attn_fwd<<<512, 256, 0, stream>>>(Qb, Kb, Vtb, mkl, Ab);

    gemm8_bf16<2><<<256, 512, 0, stream>>>(Ab, Wot, bo, out, MTOT, HHH, HHH);
}